// Round 12
// baseline (40.376 us; speedup 1.0000x reference)
//
#include <hip/hip_runtime.h>

// SITH: out[t,o,f] = subset[o] * sum_n invL_sub[o,n] * ts[t,n,f]
//   ts[t,n,f] = d[n]*ts[t-1,n,f] + decay[n]*inp[t,f]
// invL_sub row o is EXACTLY banded: nonzero only n in [4o, 4o+8] (9 taps).
// State unscaled (p = d*p + x); decay*subset folded into taps.
//
// R12 vs R11:
//  - pass2 split each 32-step chunk into 2 blocks (h=0: steps 0-15,
//    h=1: re-advance 16 recurrence-only steps then project 16-31).
//    1280 blocks -> ~2x store concurrency, zero extra P traffic.
//  - pass1 NPT=2, grid (8,51): 1632 waves (2x TLP), shorter FMA chains.

#define NF   512
#define NN   408
#define NO   100
#define NC   16     // time chunks
#define TC   32     // steps per chunk
#define NB   15     // boundary states stored (chunks 0..14)
#define TAPS 9
#define OPG  5      // outputs per o-group
#define NG   20     // o-groups (NG*OPG == NO)
#define ROWS 25     // state rows per o-group window [20g, 20g+24]
#define NPT  2      // n-rows per pass1 thread
#define TSUB 16     // projected steps per pass-2 block

// ---------------- Pass 1: chunk-boundary unscaled states ----------------
// grid (8, 51): x = f-slice (XCD), y = 8-row band. 256 thr = 64 f x 4 row-pairs.
__global__ __launch_bounds__(256) void sith_pass1(
    const float* __restrict__ inp, const float* __restrict__ d,
    float* __restrict__ P)
{
    int fs = blockIdx.x;                  // 0..7  == XCD
    int a  = blockIdx.y;                  // 0..50
    int tid = threadIdx.x;
    int lane = tid & 63;
    int y = tid >> 6;                     // 0..3
    int n0 = a * 8 + y * NPT;             // 0..406 (408 = 51*8, guard-free)
    int f = fs * 64 + lane;

    float dreg[NPT], st[NPT];
    #pragma unroll
    for (int q = 0; q < NPT; ++q) {
        dreg[q] = d[n0 + q];
        st[q] = 0.f;
    }

    const float* ip = inp + f;
    for (int b = 0; b < NB; ++b) {        // last chunk never stored
        #pragma unroll
        for (int tt = 0; tt < TC; tt += 8) {
            float x[8];
            #pragma unroll
            for (int u = 0; u < 8; ++u)
                x[u] = ip[(b * TC + tt + u) * NF];
            #pragma unroll
            for (int u = 0; u < 8; ++u) {
                #pragma unroll
                for (int q = 0; q < NPT; ++q)
                    st[q] = fmaf(dreg[q], st[q], x[u]);
            }
        }
        #pragma unroll
        for (int q = 0; q < NPT; ++q)
            P[b * (NN * NF) + (n0 + q) * NF + f] = st[q];
    }
}

// ---------------- Pass 2: half-chunk scan + banded projection ----------------
// grid (40, 32): x = oc*8 + fs (fs = bx&7 = XCD), y = c*2 + h.
// 256 thr = 4 waves; lane = f, wave w -> g = oc*4 + w (5 outputs).
// h=1 blocks re-advance 16 recurrence-only steps from the chunk boundary.
__global__ __launch_bounds__(256) void sith_pass2(
    const float* __restrict__ inp, const float* __restrict__ invL,
    const float* __restrict__ d, const float* __restrict__ decay,
    const float* __restrict__ subset, const float* __restrict__ P,
    float* __restrict__ out)
{
    int bx = blockIdx.x;                  // 0..39
    int fs = bx & 7;
    int oc = bx >> 3;                     // 0..4
    int by = blockIdx.y;                  // 0..31
    int h  = by & 1;
    int c  = by >> 1;                     // 0..15
    int tid = threadIdx.x;
    int lane = tid & 63;
    int w = tid >> 6;
    int g = oc * 4 + w;                   // 0..19
    int f = fs * 64 + lane;
    int nbase = NG * g;                   // row j -> n = nbase + j, j in [0,25)

    float dreg[ROWS], p[ROWS];
    #pragma unroll
    for (int j = 0; j < ROWS; ++j) {
        int n = nbase + j;                // <= 404 < 408: no guards
        dreg[j] = d[n];
        p[j] = (c == 0) ? 0.f : P[(c - 1) * (NN * NF) + n * NF + f];
    }

    float L[OPG][TAPS];
    #pragma unroll
    for (int k = 0; k < OPG; ++k) {
        int o = OPG * g + k;              // < 100 always
        float sub = subset[o];
        #pragma unroll
        for (int dd = 0; dd < TAPS; ++dd) {
            int n = nbase + 4 * k + dd;   // = 4o + dd, exact band
            L[k][dd] = invL[o * NN + n] * sub * decay[n];
        }
    }

    const float* ip = inp + f;
    int t0 = c * TC;

    // h=1: advance 16 recurrence-only steps (batched loads, no stores)
    if (h) {
        #pragma unroll
        for (int tt = 0; tt < TSUB; tt += 8) {
            float x[8];
            #pragma unroll
            for (int u = 0; u < 8; ++u)
                x[u] = ip[(t0 + tt + u) * NF];
            #pragma unroll
            for (int u = 0; u < 8; ++u) {
                #pragma unroll
                for (int j = 0; j < ROWS; ++j)
                    p[j] = fmaf(dreg[j], p[j], x[u]);
            }
        }
        t0 += TSUB;
    }

    int obase = (t0 * NO + OPG * g) * NF + f;

#define SITH_STEP(xv)                                                      \
    {                                                                      \
        _Pragma("unroll")                                                  \
        for (int j = 0; j < ROWS; ++j)                                     \
            p[j] = fmaf(dreg[j], p[j], (xv));                              \
        _Pragma("unroll")                                                  \
        for (int k = 0; k < OPG; ++k) {                                    \
            float acc = 0.f;                                               \
            _Pragma("unroll")                                              \
            for (int dd = 0; dd < TAPS; ++dd)                              \
                acc = fmaf(L[k][dd], p[4 * k + dd], acc);                  \
            __builtin_nontemporal_store(acc, &out[obase + k * NF]);        \
        }                                                                  \
        obase += NO * NF;                                                  \
    }

    // rotated prefetch: next 4-group's x loads issue before current steps.
    float xb0 = ip[(t0 + 0) * NF];
    float xb1 = ip[(t0 + 1) * NF];
    float xb2 = ip[(t0 + 2) * NF];
    float xb3 = ip[(t0 + 3) * NF];

    for (int tq = 0; tq < TSUB; tq += 4) {
        int tp = t0 + tq + 4;
        float xn0 = ip[((tp + 0) & 511) * NF];
        float xn1 = ip[((tp + 1) & 511) * NF];
        float xn2 = ip[((tp + 2) & 511) * NF];
        float xn3 = ip[((tp + 3) & 511) * NF];
        SITH_STEP(xb0);
        SITH_STEP(xb1);
        SITH_STEP(xb2);
        SITH_STEP(xb3);
        xb0 = xn0; xb1 = xn1; xb2 = xn2; xb3 = xn3;
    }
#undef SITH_STEP
}

extern "C" void kernel_launch(void* const* d_in, const int* in_sizes, int n_in,
                              void* d_out, int out_size, void* d_ws, size_t ws_size,
                              hipStream_t stream)
{
    const float* inp    = (const float*)d_in[0];
    const float* invL   = (const float*)d_in[1];
    const float* d      = (const float*)d_in[2];
    const float* decay  = (const float*)d_in[3];
    const float* subset = (const float*)d_in[4];
    float* out = (float*)d_out;
    float* P   = (float*)d_ws;   // 15 * 408 * 512 * 4 B = 12.5 MB boundary states

    sith_pass1<<<dim3(8, 51), 256, 0, stream>>>(inp, d, P);
    sith_pass2<<<dim3(40, 32), 256, 0, stream>>>(inp, invL, d, decay, subset, P, out);
}

// Round 13
// 36.499 us; speedup vs baseline: 1.1062x; 1.1062x over previous
//
#include <hip/hip_runtime.h>

// SITH: out[t,o,f] = subset[o] * sum_n invL_sub[o,n] * ts[t,n,f]
//   ts[t,n,f] = d[n]*ts[t-1,n,f] + decay[n]*inp[t,f]
// invL_sub row o is EXACTLY banded: nonzero only n in [4o, 4o+8] (9 taps).
// State unscaled (p = d*p + x); decay*subset folded into taps.
//
// R13 vs R11:
//  - pass1 now writes per-chunk LOCAL sums only (grid 8x26x15 = 3120 blocks,
//    each 32 steps: critical path 4 load-batches, was 60).
//  - pass2 init reconstructs the boundary state by Horner with d^32 over the
//    chunk-locals (runtime k-loop, unrolled j-loop -> registers; L2-pinned).
//  - pass2 main loop identical to R11 (XCD-pinned fs, rotated prefetch).

#define NF   512
#define NN   408
#define NO   100
#define NC   16     // time chunks
#define TC   32     // steps per chunk
#define NB   15     // chunk-local sums stored (chunks 0..14)
#define TAPS 9
#define OPG  5      // outputs per o-group
#define NG   20     // o-groups (NG*OPG == NO)
#define ROWS 25     // state rows per o-group window [20g, 20g+24]
#define NPT  4      // n-rows per pass1 thread

// ---------------- Pass 1: per-chunk LOCAL sums ----------------
// grid (8, 26, 15): x = f-slice (XCD), y = 16-row band, z = chunk.
// 256 thr = 64 f x 4 row-quads; each thread: 32 loads, 128 FMA, 4 stores.
__global__ __launch_bounds__(256) void sith_pass1(
    const float* __restrict__ inp, const float* __restrict__ d,
    float* __restrict__ P)
{
    int fs = blockIdx.x;                  // 0..7  == XCD
    int a  = blockIdx.y;                  // 0..25
    int b  = blockIdx.z;                  // 0..14
    int tid = threadIdx.x;
    int lane = tid & 63;
    int y = tid >> 6;                     // 0..3
    int n0 = a * 16 + y * NPT;
    if (n0 >= NN) return;                 // a=25, y>=2
    int f = fs * 64 + lane;

    float dreg[NPT], st[NPT];
    #pragma unroll
    for (int q = 0; q < NPT; ++q) {
        dreg[q] = d[n0 + q];
        st[q] = 0.f;
    }

    const float* ip = inp + b * TC * NF + f;
    #pragma unroll
    for (int tt = 0; tt < TC; tt += 8) {
        float x[8];
        #pragma unroll
        for (int u = 0; u < 8; ++u)
            x[u] = ip[(tt + u) * NF];
        #pragma unroll
        for (int u = 0; u < 8; ++u) {
            #pragma unroll
            for (int q = 0; q < NPT; ++q)
                st[q] = fmaf(dreg[q], st[q], x[u]);
        }
    }
    #pragma unroll
    for (int q = 0; q < NPT; ++q)
        P[b * (NN * NF) + (n0 + q) * NF + f] = st[q];
}

// ---------------- Pass 2: boundary reconstruct + scan + projection --------
// grid (40, 16): x = oc*8 + fs (fs = bx&7 = XCD), y = chunk c.
// 256 thr = 4 waves; lane = f (64 consecutive), wave w -> g = oc*4 + w.
// Boundary state S_{c-1} = Horner_{k=0..c-1}(d^32, Plocal[k]).
__global__ __launch_bounds__(256) void sith_pass2(
    const float* __restrict__ inp, const float* __restrict__ invL,
    const float* __restrict__ d, const float* __restrict__ decay,
    const float* __restrict__ subset, const float* __restrict__ P,
    float* __restrict__ out)
{
    int bx = blockIdx.x;                  // 0..39
    int fs = bx & 7;
    int oc = bx >> 3;                     // 0..4
    int c  = blockIdx.y;                  // 0..15
    int tid = threadIdx.x;
    int lane = tid & 63;
    int w = tid >> 6;
    int g = oc * 4 + w;                   // 0..19
    int f = fs * 64 + lane;
    int nbase = NG * g;                   // row j -> n = nbase + j, j in [0,25)

    float dreg[ROWS], p[ROWS];
    #pragma unroll
    for (int j = 0; j < ROWS; ++j)
        dreg[j] = d[nbase + j];           // n <= 404 < 408: no guards

    // boundary reconstruction from chunk-locals (L2-pinned on this XCD)
    if (c == 0) {
        #pragma unroll
        for (int j = 0; j < ROWS; ++j) p[j] = 0.f;
    } else {
        float d32[ROWS];
        #pragma unroll
        for (int j = 0; j < ROWS; ++j) {
            float d2 = dreg[j] * dreg[j];
            float d4 = d2 * d2, d8 = d4 * d4, d16 = d8 * d8;
            d32[j] = d16 * d16;
        }
        const float* Pb = P + nbase * NF + f;
        #pragma unroll
        for (int j = 0; j < ROWS; ++j)
            p[j] = Pb[j * NF];            // Plocal[0]
        for (int k = 1; k < c; ++k) {     // runtime trip count 0..14
            const float* Pk = Pb + k * (NN * NF);
            #pragma unroll
            for (int j = 0; j < ROWS; ++j)
                p[j] = fmaf(d32[j], p[j], Pk[j * NF]);
        }
    }

    float L[OPG][TAPS];
    #pragma unroll
    for (int k = 0; k < OPG; ++k) {
        int o = OPG * g + k;              // < 100 always
        float sub = subset[o];
        #pragma unroll
        for (int dd = 0; dd < TAPS; ++dd) {
            int n = nbase + 4 * k + dd;   // = 4o + dd, exact band
            L[k][dd] = invL[o * NN + n] * sub * decay[n];
        }
    }

    const float* ip = inp + f;
    int t0 = c * TC;
    int obase = (t0 * NO + OPG * g) * NF + f;

#define SITH_STEP(xv)                                                      \
    {                                                                      \
        _Pragma("unroll")                                                  \
        for (int j = 0; j < ROWS; ++j)                                     \
            p[j] = fmaf(dreg[j], p[j], (xv));                              \
        _Pragma("unroll")                                                  \
        for (int k = 0; k < OPG; ++k) {                                    \
            float acc = 0.f;                                               \
            _Pragma("unroll")                                              \
            for (int dd = 0; dd < TAPS; ++dd)                              \
                acc = fmaf(L[k][dd], p[4 * k + dd], acc);                  \
            __builtin_nontemporal_store(acc, &out[obase + k * NF]);        \
        }                                                                  \
        obase += NO * NF;                                                  \
    }

    // rotated prefetch: next 4-group's x loads issue before current steps.
    float xb0 = ip[(t0 + 0) * NF];
    float xb1 = ip[(t0 + 1) * NF];
    float xb2 = ip[(t0 + 2) * NF];
    float xb3 = ip[(t0 + 3) * NF];

    for (int tq = 0; tq < TC; tq += 4) {
        int tp = t0 + tq + 4;
        float xn0 = ip[((tp + 0) & 511) * NF];
        float xn1 = ip[((tp + 1) & 511) * NF];
        float xn2 = ip[((tp + 2) & 511) * NF];
        float xn3 = ip[((tp + 3) & 511) * NF];
        SITH_STEP(xb0);
        SITH_STEP(xb1);
        SITH_STEP(xb2);
        SITH_STEP(xb3);
        xb0 = xn0; xb1 = xn1; xb2 = xn2; xb3 = xn3;
    }
#undef SITH_STEP
}

extern "C" void kernel_launch(void* const* d_in, const int* in_sizes, int n_in,
                              void* d_out, int out_size, void* d_ws, size_t ws_size,
                              hipStream_t stream)
{
    const float* inp    = (const float*)d_in[0];
    const float* invL   = (const float*)d_in[1];
    const float* d      = (const float*)d_in[2];
    const float* decay  = (const float*)d_in[3];
    const float* subset = (const float*)d_in[4];
    float* out = (float*)d_out;
    float* P   = (float*)d_ws;   // 15 * 408 * 512 * 4 B = 12.5 MB chunk-local sums

    sith_pass1<<<dim3(8, 26, NB), 256, 0, stream>>>(inp, d, P);
    sith_pass2<<<dim3(40, NC), 256, 0, stream>>>(inp, invL, d, decay, subset, P, out);
}

// Round 14
// 36.383 us; speedup vs baseline: 1.1097x; 1.0032x over previous
//
#include <hip/hip_runtime.h>

// SITH: out[t,o,f] = subset[o] * sum_n invL_sub[o,n] * ts[t,n,f]
//   ts[t,n,f] = d[n]*ts[t-1,n,f] + decay[n]*inp[t,f]
// invL_sub row o is EXACTLY banded: nonzero only n in [4o, 4o+8] (9 taps).
// State unscaled (p = d*p + x); decay*subset folded into taps.
//
// R14 vs R13 (single change): pass2 stores batched per 4-step group.
// acc[4][5] accumulated in registers, then 20 back-to-back nt stores ->
// 4x per-wave store MLP (1.25 KB -> 5 KB bursts). Everything else identical.

#define NF   512
#define NN   408
#define NO   100
#define NC   16     // time chunks
#define TC   32     // steps per chunk
#define NB   15     // chunk-local sums stored (chunks 0..14)
#define TAPS 9
#define OPG  5      // outputs per o-group
#define NG   20     // o-groups (NG*OPG == NO)
#define ROWS 25     // state rows per o-group window [20g, 20g+24]
#define NPT  4      // n-rows per pass1 thread

// ---------------- Pass 1: per-chunk LOCAL sums ----------------
// grid (8, 26, 15): x = f-slice (XCD), y = 16-row band, z = chunk.
__global__ __launch_bounds__(256) void sith_pass1(
    const float* __restrict__ inp, const float* __restrict__ d,
    float* __restrict__ P)
{
    int fs = blockIdx.x;                  // 0..7  == XCD
    int a  = blockIdx.y;                  // 0..25
    int b  = blockIdx.z;                  // 0..14
    int tid = threadIdx.x;
    int lane = tid & 63;
    int y = tid >> 6;                     // 0..3
    int n0 = a * 16 + y * NPT;
    if (n0 >= NN) return;                 // a=25, y>=2
    int f = fs * 64 + lane;

    float dreg[NPT], st[NPT];
    #pragma unroll
    for (int q = 0; q < NPT; ++q) {
        dreg[q] = d[n0 + q];
        st[q] = 0.f;
    }

    const float* ip = inp + b * TC * NF + f;
    #pragma unroll
    for (int tt = 0; tt < TC; tt += 8) {
        float x[8];
        #pragma unroll
        for (int u = 0; u < 8; ++u)
            x[u] = ip[(tt + u) * NF];
        #pragma unroll
        for (int u = 0; u < 8; ++u) {
            #pragma unroll
            for (int q = 0; q < NPT; ++q)
                st[q] = fmaf(dreg[q], st[q], x[u]);
        }
    }
    #pragma unroll
    for (int q = 0; q < NPT; ++q)
        P[b * (NN * NF) + (n0 + q) * NF + f] = st[q];
}

// ---------------- Pass 2: boundary reconstruct + scan + projection --------
// grid (40, 16): x = oc*8 + fs (fs = bx&7 = XCD), y = chunk c.
// 256 thr = 4 waves; lane = f (64 consecutive), wave w -> g = oc*4 + w.
// Boundary state S_{c-1} = Horner_{k=0..c-1}(d^32, Plocal[k]).
__global__ __launch_bounds__(256) void sith_pass2(
    const float* __restrict__ inp, const float* __restrict__ invL,
    const float* __restrict__ d, const float* __restrict__ decay,
    const float* __restrict__ subset, const float* __restrict__ P,
    float* __restrict__ out)
{
    int bx = blockIdx.x;                  // 0..39
    int fs = bx & 7;
    int oc = bx >> 3;                     // 0..4
    int c  = blockIdx.y;                  // 0..15
    int tid = threadIdx.x;
    int lane = tid & 63;
    int w = tid >> 6;
    int g = oc * 4 + w;                   // 0..19
    int f = fs * 64 + lane;
    int nbase = NG * g;                   // row j -> n = nbase + j, j in [0,25)

    float dreg[ROWS], p[ROWS];
    #pragma unroll
    for (int j = 0; j < ROWS; ++j)
        dreg[j] = d[nbase + j];           // n <= 404 < 408: no guards

    // boundary reconstruction from chunk-locals (L2-pinned on this XCD)
    if (c == 0) {
        #pragma unroll
        for (int j = 0; j < ROWS; ++j) p[j] = 0.f;
    } else {
        float d32[ROWS];
        #pragma unroll
        for (int j = 0; j < ROWS; ++j) {
            float d2 = dreg[j] * dreg[j];
            float d4 = d2 * d2, d8 = d4 * d4, d16 = d8 * d8;
            d32[j] = d16 * d16;
        }
        const float* Pb = P + nbase * NF + f;
        #pragma unroll
        for (int j = 0; j < ROWS; ++j)
            p[j] = Pb[j * NF];            // Plocal[0]
        for (int k = 1; k < c; ++k) {     // runtime trip count 0..14
            const float* Pk = Pb + k * (NN * NF);
            #pragma unroll
            for (int j = 0; j < ROWS; ++j)
                p[j] = fmaf(d32[j], p[j], Pk[j * NF]);
        }
    }

    float L[OPG][TAPS];
    #pragma unroll
    for (int k = 0; k < OPG; ++k) {
        int o = OPG * g + k;              // < 100 always
        float sub = subset[o];
        #pragma unroll
        for (int dd = 0; dd < TAPS; ++dd) {
            int n = nbase + 4 * k + dd;   // = 4o + dd, exact band
            L[k][dd] = invL[o * NN + n] * sub * decay[n];
        }
    }

    const float* ip = inp + f;
    int t0 = c * TC;
    int obase = (t0 * NO + OPG * g) * NF + f;

    // one step: recurrence + accumulate projections into acc[s][*]
#define SITH_STEP(s, xv)                                                   \
    {                                                                      \
        _Pragma("unroll")                                                  \
        for (int j = 0; j < ROWS; ++j)                                     \
            p[j] = fmaf(dreg[j], p[j], (xv));                              \
        _Pragma("unroll")                                                  \
        for (int k = 0; k < OPG; ++k) {                                    \
            float a0 = 0.f;                                                \
            _Pragma("unroll")                                              \
            for (int dd = 0; dd < TAPS; ++dd)                              \
                a0 = fmaf(L[k][dd], p[4 * k + dd], a0);                    \
            acc[s][k] = a0;                                                \
        }                                                                  \
    }

    // rotated prefetch: next 4-group's x loads issue before current steps.
    float xb0 = ip[(t0 + 0) * NF];
    float xb1 = ip[(t0 + 1) * NF];
    float xb2 = ip[(t0 + 2) * NF];
    float xb3 = ip[(t0 + 3) * NF];

    for (int tq = 0; tq < TC; tq += 4) {
        int tp = t0 + tq + 4;
        float xn0 = ip[((tp + 0) & 511) * NF];
        float xn1 = ip[((tp + 1) & 511) * NF];
        float xn2 = ip[((tp + 2) & 511) * NF];
        float xn3 = ip[((tp + 3) & 511) * NF];

        float acc[4][OPG];
        SITH_STEP(0, xb0);
        SITH_STEP(1, xb1);
        SITH_STEP(2, xb2);
        SITH_STEP(3, xb3);

        // burst: 20 back-to-back stores (5 KB in flight per wave)
        #pragma unroll
        for (int s = 0; s < 4; ++s) {
            #pragma unroll
            for (int k = 0; k < OPG; ++k)
                __builtin_nontemporal_store(acc[s][k],
                    &out[obase + (s * NO + k) * NF]);
        }
        obase += 4 * NO * NF;

        xb0 = xn0; xb1 = xn1; xb2 = xn2; xb3 = xn3;
    }
#undef SITH_STEP
}

extern "C" void kernel_launch(void* const* d_in, const int* in_sizes, int n_in,
                              void* d_out, int out_size, void* d_ws, size_t ws_size,
                              hipStream_t stream)
{
    const float* inp    = (const float*)d_in[0];
    const float* invL   = (const float*)d_in[1];
    const float* d      = (const float*)d_in[2];
    const float* decay  = (const float*)d_in[3];
    const float* subset = (const float*)d_in[4];
    float* out = (float*)d_out;
    float* P   = (float*)d_ws;   // 15 * 408 * 512 * 4 B = 12.5 MB chunk-local sums

    sith_pass1<<<dim3(8, 26, NB), 256, 0, stream>>>(inp, d, P);
    sith_pass2<<<dim3(40, NC), 256, 0, stream>>>(inp, invL, d, decay, subset, P, out);
}